// Round 13
// baseline (83.810 us; speedup 1.0000x reference)
//
#include <hip/hip_runtime.h>
#include <hip/hip_bf16.h>
#include <math.h>

#define B 4
#define T 8
#define NF 8192
#define C 384
#define H 12
#define TOPK 32
#define D 32
#define STOT (T + NF)          // 8200
#define R (H * T)              // 96 score rows per batch
#define KSEL 48                // selection margin (bf16 keys -> exact fp32 rescore)
#define NCH 4                  // selection chunks per row
#define CHSZ (NF / NCH)        // 2048
#define SCALE 0.17677669529663687f

typedef unsigned int uint;
typedef unsigned short ushort;
typedef short bf16x8 __attribute__((ext_vector_type(8)));
typedef float f32x4 __attribute__((ext_vector_type(4)));

__device__ __forceinline__ ushort bf16u(float a) {
  return __builtin_bit_cast(ushort, __float2bfloat16(a));
}

// order-preserving u16 key from f32 (bf16 RNE, sign-flip encode)
__device__ __forceinline__ ushort f32_key(float s) {
  uint kb = bf16u(s);
  kb ^= (kb & 0x8000u) ? 0xFFFFu : 0x8000u;
  return (ushort)kb;
}

// ---------------------------------------------------------------------------
// Kernel 1a: q-projection. grid (T, 6 o-tiles, 2 k-halves), 256 thr.
// ---------------------------------------------------------------------------
__global__ __launch_bounds__(256) void ta_qproj_kernel(
    const float* __restrict__ x, const float* __restrict__ qs_w,
    float* __restrict__ q_part) {
  int t = blockIdx.x;
  int o0 = blockIdx.y * 64;
  int z = blockIdx.z;
  int tid = threadIdx.x;
  int o = tid & 63, ks = tid >> 6;
  __shared__ float xs[B][192];
  __shared__ float part[4][B][64];
  if (tid < 192) {
    int b = tid / 48, j4 = (tid % 48) * 4;
    *reinterpret_cast<float4*>(&xs[b][j4]) =
        *reinterpret_cast<const float4*>(x + ((size_t)b * STOT + t) * C + z * 192 + j4);
  }
  __syncthreads();
  float a0 = 0.f, a1 = 0.f, a2 = 0.f, a3 = 0.f;
  const float* w = qs_w + (size_t)t * C * C + (size_t)(z * 192 + ks * 48) * C + o0 + o;
#pragma unroll 8
  for (int c = 0; c < 48; ++c) {
    float wv = w[(size_t)c * C];
    int cj = ks * 48 + c;
    a0 += xs[0][cj] * wv;
    a1 += xs[1][cj] * wv;
    a2 += xs[2][cj] * wv;
    a3 += xs[3][cj] * wv;
  }
  part[ks][0][o] = a0; part[ks][1][o] = a1;
  part[ks][2][o] = a2; part[ks][3][o] = a3;
  __syncthreads();
  {
    int b = tid >> 6, oo = tid & 63;
    float s = part[0][b][oo] + part[1][b][oo] + part[2][b][oo] + part[3][b][oo];
    q_part[(((size_t)z * B + b) * T + t) * C + o0 + oo] = s;
  }
}

// ---------------------------------------------------------------------------
// Kernel 1b: fold k-projection. grid B*H, 384 thr (thread = c).
// ---------------------------------------------------------------------------
__global__ __launch_bounds__(384) void ta_fold_kernel(
    const float* __restrict__ q_part, const float* __restrict__ kv_w,
    float* __restrict__ qk_f32, ushort* __restrict__ qk_bf) {
  int b = blockIdx.x / H, h = blockIdx.x % H;
  int tid = threadIdx.x;
  __shared__ float kS[C][33];
  __shared__ float qh[T][D];
  if (tid < T * D) {
    int t = tid >> 5, d = tid & 31;
    qh[t][d] = q_part[((size_t)b * T + t) * C + h * D + d] +
               q_part[(((size_t)B + b) * T + t) * C + h * D + d];
  }
  for (int j = tid; j < C * 8; j += 384) {
    int c = j >> 3, d4 = (j & 7) * 4;
    float4 v = *reinterpret_cast<const float4*>(
        kv_w + (size_t)c * (2 * C) + h * D + d4);
    kS[c][d4 + 0] = v.x; kS[c][d4 + 1] = v.y;
    kS[c][d4 + 2] = v.z; kS[c][d4 + 3] = v.w;
  }
  __syncthreads();
  float acc[T] = {0.f, 0.f, 0.f, 0.f, 0.f, 0.f, 0.f, 0.f};
#pragma unroll
  for (int d = 0; d < D; ++d) {
    float kv = kS[tid][d];
#pragma unroll
    for (int t = 0; t < T; ++t) acc[t] += qh[t][d] * kv;
  }
#pragma unroll
  for (int t = 0; t < T; ++t) {
    size_t off = ((size_t)b * R + (size_t)h * T + t) * C + tid;
    float a = acc[t];
    qk_f32[off] = a;
    qk_bf[off] = bf16u(a);
  }
}

// ---------------------------------------------------------------------------
// Kernel 2: bf16 MFMA scores -> u16 sort-keys + overlapped d_out zeroing.
// ---------------------------------------------------------------------------
__global__ __launch_bounds__(256) void ta_scores_kernel(
    const float* __restrict__ x, const ushort* __restrict__ qk_bf,
    ushort* __restrict__ keys, float4* __restrict__ out4) {
  int b = blockIdx.y;
  int n0 = blockIdx.x * 64;
  int tid = threadIdx.x;
  int lane = tid & 63, w = tid >> 6;
  int row16 = lane & 15, kg = lane >> 4;
  __shared__ ushort fS[64][72];
  __shared__ ushort qS[96][72];
  f32x4 acc[6];
#pragma unroll
  for (int i = 0; i < 6; ++i) acc[i] = (f32x4){0.f, 0.f, 0.f, 0.f};

  // zero my slice of d_out; stores drain under the MFMA loop below.
  {
    const int SL = (B * STOT * C / 4) / 512;  // 6150
    int zbid = blockIdx.y * gridDim.x + blockIdx.x;
    float4 z = {0.f, 0.f, 0.f, 0.f};
    float4* dst = out4 + (size_t)zbid * SL;
    for (int j = tid; j < SL; j += 256) dst[j] = z;
  }

  const float* xb = x + ((size_t)b * STOT + T + n0) * C;
  const ushort* qb = qk_bf + (size_t)b * R * C;

  int frow = tid >> 2, fcg = (tid & 3) * 8;

#pragma unroll 1
  for (int c0 = 0; c0 < C; c0 += 32) {
    {
      const float* src = xb + (size_t)frow * C + c0 + fcg;
      float4 v0 = *reinterpret_cast<const float4*>(src);
      float4 v1 = *reinterpret_cast<const float4*>(src + 4);
      uint4 p;
      p.x = (uint)bf16u(v0.x) | ((uint)bf16u(v0.y) << 16);
      p.y = (uint)bf16u(v0.z) | ((uint)bf16u(v0.w) << 16);
      p.z = (uint)bf16u(v1.x) | ((uint)bf16u(v1.y) << 16);
      p.w = (uint)bf16u(v1.z) | ((uint)bf16u(v1.w) << 16);
      *reinterpret_cast<uint4*>(&fS[frow][fcg]) = p;
    }
#pragma unroll
    for (int s = 0; s < 2; ++s) {
      int u = tid + 256 * s;
      if (u < 384) {
        int row = u >> 2, cg = (u & 3) * 8;
        uint4 v = *reinterpret_cast<const uint4*>(qb + (size_t)row * C + c0 + cg);
        *reinterpret_cast<uint4*>(&qS[row][cg]) = v;
      }
    }
    __syncthreads();
    bf16x8 bfr = *reinterpret_cast<const bf16x8*>(&fS[w * 16 + row16][kg * 8]);
#pragma unroll
    for (int i = 0; i < 6; ++i) {
      bf16x8 afr = *reinterpret_cast<const bf16x8*>(&qS[i * 16 + row16][kg * 8]);
      acc[i] = __builtin_amdgcn_mfma_f32_16x16x32_bf16(afr, bfr, acc[i], 0, 0, 0);
    }
    __syncthreads();
  }
  int n = n0 + w * 16 + row16;
#pragma unroll
  for (int i = 0; i < 6; ++i) {
    int rbase = i * 16 + kg * 4;
#pragma unroll
    for (int reg = 0; reg < 4; ++reg) {
      keys[((size_t)b * R + rbase + reg) * NF + n] = f32_key(acc[i][reg] * SCALE);
    }
  }
}

// ---------------------------------------------------------------------------
// Kernel 3a: per (row, 2048-key chunk): exact local top-48 via 12-bit hist +
// pivot + rank; writes 48 packed u32 (key<<13 | 8191-gidx) to cand_buf.
// Grid (NCH, B*R) = 1536 blocks, 256 thr.
// ---------------------------------------------------------------------------
__global__ __launch_bounds__(256) void ta_selchunk_kernel(
    const ushort* __restrict__ keys, uint* __restrict__ cand_buf) {
  int ch = blockIdx.x, rr = blockIdx.y;
  int tid = threadIdx.x;
  int lane = tid & 63, wvi = tid >> 6;   // 4 waves
  __shared__ uint hist[4096];     // 16 KB
  __shared__ uint cand[CHSZ];     // 8 KB (worst-case exact-safe)
  __shared__ uint wtot[4];
  __shared__ uint sh_piv, cnt;
  const ushort* kp = keys + (size_t)rr * NF + (size_t)ch * CHSZ;

  {
    uint4 z4 = {0u, 0u, 0u, 0u};
    uint4* hz = reinterpret_cast<uint4*>(hist);
    for (int i = tid; i < 1024; i += 256) hz[i] = z4;
  }
  if (tid == 0) cnt = 0;
  __syncthreads();
  for (int i = tid; i < CHSZ; i += 256) atomicAdd(&hist[kp[i] >> 4], 1u);
  __syncthreads();

  // suffix-scan over 4096 bins: thread t owns bins [16t, 16t+16)
  uint pp = 0;
#pragma unroll
  for (int j = 0; j < 16; ++j) pp += hist[tid * 16 + j];
  uint suf = pp;
#pragma unroll
  for (int off = 1; off < 64; off <<= 1) {
    uint o = __shfl_down(suf, off);
    if (lane + off < 64) suf += o;
  }
  if (lane == 0) wtot[wvi] = suf;
  __syncthreads();
  {
    uint later = 0;
    for (int wq = wvi + 1; wq < 4; ++wq) later += wtot[wq];
    uint geg = later + suf;        // sum of bins >= 16*tid
    uint gng = geg - pp;           // sum of bins >= 16*(tid+1)
    if (geg >= (uint)KSEL && gng < (uint)KSEL) {
      uint run = gng;
      int pv = 0;
      for (int j = 15; j >= 0; --j) {
        uint c = hist[tid * 16 + j];
        uint nrun = run + c;
        if (nrun >= (uint)KSEL && run < (uint)KSEL) pv = tid * 16 + j;
        run = nrun;
      }
      sh_piv = (uint)pv;
    }
  }
  __syncthreads();
  uint piv = sh_piv;
  for (int i = tid; i < CHSZ; i += 256) {
    uint u = kp[i];
    if ((u >> 4) >= piv) {
      uint s = atomicAdd(&cnt, 1u);
      cand[s] = (u << 13) | (8191u - (uint)(ch * CHSZ + i));
    }
  }
  __syncthreads();
  uint m = cnt;
  for (int i2 = tid; i2 < (int)m; i2 += 256) {
    uint me = cand[i2];
    int r = 0;
    for (uint e = 0; e < m; ++e) r += (cand[e] > me);
    if (r < KSEL) cand_buf[((size_t)rr * NCH + ch) * KSEL + r] = me;
  }
}

// ---------------------------------------------------------------------------
// Kernel 3b: merge 4x48 packed candidates (direct 192-rank, no hist), exact
// fp32 rescore of top-48, softmax, then light tail: fbar -> att -> scatter.
// Grid = B*R = 384 blocks, 384 thr.
// ---------------------------------------------------------------------------
__global__ __launch_bounds__(384) void ta_mergetail_kernel(
    const uint* __restrict__ cand_buf, const float* __restrict__ x,
    const float* __restrict__ qk_f32, const float* __restrict__ kv_w,
    const float* __restrict__ ew, float* __restrict__ out) {
  constexpr int M = NCH * KSEL;  // 192
  int rr = blockIdx.x;
  int t = rr % T, h = (rr / T) % H, b = rr / R;
  int hD = h * D;
  int tid = threadIdx.x;
  __shared__ uint candS[M];
  __shared__ int il[KSEL];
  __shared__ float sv[KSEL];
  __shared__ int rkS[KSEL];
  __shared__ float qS[C];
  __shared__ float wl[TOPK];
  __shared__ int top_il[TOPK];
  __shared__ float fbarS[C];
  __shared__ float gS[TOPK][D];
  __shared__ float part[8][D];
  __shared__ __align__(16) float attS[D];
  __shared__ float smax, esum;

  if (tid < M) candS[tid] = cand_buf[(size_t)rr * M + tid];
  qS[tid] = qk_f32[(size_t)rr * C + tid];
  __syncthreads();
  if (tid < M) {
    uint me = candS[tid];
    int r = 0;
#pragma unroll 8
    for (int e = 0; e < M; ++e) r += (candS[e] > me);
    if (r < KSEL) il[r] = 8191 - (int)(me & 8191u);
  }
  __syncthreads();

  // exact fp32 rescore of the 48 candidates (8 threads per candidate)
  {
    int k = tid >> 3, j = tid & 7;
    const float* fp = x + ((size_t)b * STOT + T + il[k]) * C + j;
    float s = 0.f;
#pragma unroll 8
    for (int m2 = 0; m2 < 48; ++m2) s += fp[m2 * 8] * qS[j + m2 * 8];
    s += __shfl_down(s, 4);
    s += __shfl_down(s, 2);
    s += __shfl_down(s, 1);
    if (j == 0) sv[k] = s * SCALE;
  }
  __syncthreads();
  if (tid < KSEL) {
    float mys = sv[tid];
    int myn = il[tid];
    int r = 0;
#pragma unroll
    for (int e = 0; e < KSEL; ++e) {
      float se = sv[e];
      r += (se > mys) || (se == mys && il[e] < myn);
    }
    rkS[tid] = r;
    if (r == 0) smax = mys;
  }
  __syncthreads();
  {
    float e = 0.f;
    if (tid < KSEL && rkS[tid] < TOPK) e = expf(sv[tid] - smax);
    if (tid < 64) {
      float t2 = e;
#pragma unroll
      for (int off = 32; off; off >>= 1) t2 += __shfl_down(t2, off);
      if (tid == 0) esum = t2;
    }
    __syncthreads();
    if (tid < KSEL && rkS[tid] < TOPK) {
      wl[rkS[tid]] = e / esum;
      top_il[rkS[tid]] = il[tid];
    }
  }
  __syncthreads();

  // ---- tail: fbar + g extraction (thread = column c) ----
  {
    float fbar = 0.f;
    bool ing = (tid >= hD) && (tid < hD + D);
#pragma unroll 4
    for (int k = 0; k < TOPK; ++k) {
      float v = x[((size_t)b * STOT + T + top_il[k]) * C + tid];
      float wv = wl[k] * v;
      fbar += wv;
      if (ing) gS[k][tid - hD] = wv;
    }
    fbarS[tid] = fbar;
  }
  __syncthreads();

  // att: 256 threads = 32 d x 8 segs of 48 c; Vw reads 128B-coalesced
  if (tid < 256) {
    int d = tid & 31, seg = tid >> 5;
    const float* vw = kv_w + C + hD + d;   // kv_w[c][C+hD+d], row stride 2C
    float a0 = 0.f, a1 = 0.f;
    int cb = seg * 48;
#pragma unroll 8
    for (int c = 0; c < 48; c += 2) {
      a0 += fbarS[cb + c] * vw[(size_t)(cb + c) * (2 * C)];
      a1 += fbarS[cb + c + 1] * vw[(size_t)(cb + c + 1) * (2 * C)];
    }
    part[seg][d] = a0 + a1;
  }
  __syncthreads();
  if (tid < D) {
    float a = 0.f;
#pragma unroll
    for (int s = 0; s < 8; ++s) a += part[s][tid];
    attS[tid] = a;
  }
  __syncthreads();

  // ---- scatter: thread = output column o = tid, 33 atomic rows ----
  float ewc[D];
  const float* ewt = ew + (size_t)t * C * C + (size_t)hD * C + tid;
#pragma unroll
  for (int dd = 0; dd < D; ++dd) ewc[dd] = ewt[(size_t)dd * C];
  size_t obase = (size_t)b * STOT * C + tid;
#pragma unroll 1
  for (int kk = 0; kk < TOPK; ++kk) {
    float y = 0.f;
#pragma unroll
    for (int d4 = 0; d4 < D; d4 += 4) {
      float4 g4 = *reinterpret_cast<const float4*>(&gS[kk][d4]);
      y += g4.x * ewc[d4] + g4.y * ewc[d4 + 1] +
           g4.z * ewc[d4 + 2] + g4.w * ewc[d4 + 3];
    }
    atomicAdd(&out[obase + (size_t)(T + top_il[kk]) * C], y);
  }
  {
    float y = 0.f;
#pragma unroll
    for (int d4 = 0; d4 < D; d4 += 4) {
      float4 a4 = *reinterpret_cast<const float4*>(attS + d4);
      y += a4.x * ewc[d4] + a4.y * ewc[d4 + 1] +
           a4.z * ewc[d4 + 2] + a4.w * ewc[d4 + 3];
    }
    atomicAdd(&out[obase + (size_t)t * C], y);
  }
}

// ---------------------------------------------------------------------------
extern "C" void kernel_launch(void* const* d_in, const int* in_sizes, int n_in,
                              void* d_out, int out_size, void* d_ws, size_t ws_size,
                              hipStream_t stream) {
  const float* x = (const float*)d_in[0];
  const float* qs_w = (const float*)d_in[1];
  const float* kv_w = (const float*)d_in[2];
  const float* ew = (const float*)d_in[3];
  float* out = (float*)d_out;

  char* p = (char*)d_ws;
  float* qk_f32 = (float*)p;  p += (size_t)B * R * C * 4;            // 589824
  ushort* qk_bf = (ushort*)p; p += (size_t)B * R * C * 2;            // 294912
  ushort* keys = (ushort*)p;  p += (size_t)B * R * NF * 2;           // 6291456
  uint* cand_buf = (uint*)p;  p += (size_t)B * R * NCH * KSEL * 4;   // 294912
  float* q_part = (float*)p;  // 2*B*T*C floats

  dim3 gq(T, C / 64, 2);
  ta_qproj_kernel<<<gq, 256, 0, stream>>>(x, qs_w, q_part);
  ta_fold_kernel<<<B * H, 384, 0, stream>>>(q_part, kv_w, qk_f32, qk_bf);
  dim3 g2(NF / 64, B);
  ta_scores_kernel<<<g2, 256, 0, stream>>>(x, qk_bf, keys, (float4*)out);
  dim3 gs(NCH, B * R);
  ta_selchunk_kernel<<<gs, 256, 0, stream>>>(keys, cand_buf);
  ta_mergetail_kernel<<<B * R, 384, 0, stream>>>(cand_buf, x, qk_f32, kv_w, ew, out);
}